// Round 3
// baseline (186.854 us; speedup 1.0000x reference)
//
#include <hip/hip_runtime.h>
#include <stdint.h>

// ---------------------------------------------------------------------------
// Types
// ---------------------------------------------------------------------------
typedef __attribute__((ext_vector_type(8))) __bf16 bf16x8;
typedef __attribute__((ext_vector_type(8))) unsigned short u16x8;
typedef __attribute__((ext_vector_type(4))) unsigned short u16x4;
typedef __attribute__((ext_vector_type(4))) short s16x4;
typedef __attribute__((ext_vector_type(4))) float f32x4;

typedef unsigned int u32_as1 __attribute__((address_space(1)));
typedef unsigned int u32_as3 __attribute__((address_space(3)));

// fp32 -> bf16 round-to-nearest-even (inputs are finite normals; no NaN path)
__device__ __forceinline__ unsigned short f2bf(float f) {
  unsigned int u = __float_as_uint(f);
  u += 0x7fffu + ((u >> 16) & 1u);
  return (unsigned short)(u >> 16);
}

__device__ __forceinline__ bf16x8 ld_frag(const unsigned short* p) {
  return __builtin_bit_cast(bf16x8, *(const u16x8*)p);
}

// K=16 bf16 MFMA: A/B are 4 bf16 (as short4). C row=quad*4+r, col=lane&15;
// A[m=lane&15][k=quad*4+j]; B[k=quad*4+j][n=lane&15].
__device__ __forceinline__ f32x4 mfma16(s16x4 a, s16x4 b, f32x4 c) {
#if __has_builtin(__builtin_amdgcn_mfma_f32_16x16x16bf16_1k)
  return __builtin_amdgcn_mfma_f32_16x16x16bf16_1k(a, b, c, 0, 0, 0);
#elif __has_builtin(__builtin_amdgcn_mfma_f32_16x16x16_bf16_1k)
  return __builtin_amdgcn_mfma_f32_16x16x16_bf16_1k(a, b, c, 0, 0, 0);
#else
  asm volatile("v_mfma_f32_16x16x16_bf16 %0, %1, %2, %0"
               : "+v"(c) : "v"(a), "v"(b));
  return c;
#endif
}

__device__ __forceinline__ float fast_exp2(float x) {
#if __has_builtin(__builtin_amdgcn_exp2f)
  return __builtin_amdgcn_exp2f(x);
#else
  return exp2f(x);
#endif
}

// async global->LDS, 16B per lane. LDS dest must be wave-uniform base +
// lane*16B (linear); swizzled layouts come from pre-swizzling the per-lane
// GLOBAL source address (m97/m173 pattern).
__device__ __forceinline__ void async16(const void* g, void* l) {
  const u32_as1* gp = (const u32_as1*)(uintptr_t)g;
  u32_as3* lp = (u32_as3*)(uintptr_t)l;
  __builtin_amdgcn_global_load_lds(gp, lp, 16, 0, 0);
}

template <int N> __device__ __forceinline__ void wait_vmcnt() {
  if constexpr (N == 0)      asm volatile("s_waitcnt vmcnt(0)" ::: "memory");
  else if constexpr (N == 4) asm volatile("s_waitcnt vmcnt(4)" ::: "memory");
  else if constexpr (N == 5) asm volatile("s_waitcnt vmcnt(5)" ::: "memory");
}

// ---------------------------------------------------------------------------
// Kernel 1: fused prep — x fp32->bf16, w_qkv / w_proj transpose+cast.
// ---------------------------------------------------------------------------
__global__ __launch_bounds__(256) void prep_kernel(
    const float* __restrict__ x, const float* __restrict__ w_qkv,
    const float* __restrict__ w_proj, u16x4* __restrict__ x_bf,
    unsigned short* __restrict__ wqkvT, unsigned short* __restrict__ wprojT) {
  const int bid = blockIdx.x;
  const int t = threadIdx.x;
  if (bid < 6144) {  // convert: 6144*256 float4 = 6,291,456 float4
    const int i = bid * 256 + t;
    float4 v = ((const float4*)x)[i];
    u16x4 o;
    o[0] = f2bf(v.x); o[1] = f2bf(v.y); o[2] = f2bf(v.z); o[3] = f2bf(v.w);
    x_bf[i] = o;
    return;
  }
  // transpose+cast, 32x32 tiles with flat 256 threads
  __shared__ float tile[32][33];
  const float* w; unsigned short* wt; int N, bx, by;
  if (bid < 6144 + 1728) { const int r = bid - 6144; w = w_qkv; wt = wqkvT; N = 2304; bx = r % 72; by = r / 72; }
  else                   { const int r = bid - 7872; w = w_proj; wt = wprojT; N = 768; bx = r % 24; by = r / 24; }
  const int n0 = bx * 32, k0 = by * 32;
  const int tx = t & 31, ty = t >> 5;
#pragma unroll
  for (int r = 0; r < 4; r++)
    tile[ty + r * 8][tx] = w[(k0 + ty + r * 8) * N + n0 + tx];
  __syncthreads();
#pragma unroll
  for (int r = 0; r < 4; r++)
    wt[(n0 + ty + r * 8) * 768 + k0 + tx] = f2bf(tile[tx][ty + r * 8]);
}

// ---------------------------------------------------------------------------
// Kernel 2/4: GEMM  C[M, 192-col tile] = A[M,768] * Bt[N,768]^T
// 128x192 tile, BK=64, 8 waves (512 thr) as 2m x 4n; wave C = 64x48
// (acc[4][3] f32x4 = 48 regs).
// Schedule (the round-2 post-mortem fixes):
//  * ONE barrier per K-tile (not per phase). Only cross-wave hazard is the
//    stage(kt+2) DMA overwriting buf (kt+2)%3, last read at tile kt-1 —
//    the tile-top barrier proves all waves are past that. Inside a tile each
//    wave runs free: 14 ds_reads then 24 MFMAs, compiler interleaves via
//    fine-grained lgkmcnt; waves slip up to a tile so LDS and MFMA pipes of
//    different waves overlap instead of burst-colliding.
//  * 3 LDS stages (120 KB), prefetch distance 2, counted vmcnt(5): stage
//    issue is FIRST after the barrier, so at tile-kt top the only in-flight
//    loads are stage(kt+1)'s 5 -> vmcnt(5) == "stage(kt) landed". Never
//    drains to 0 until the last tile.
//  * Grid has ZERO round quantization: QKV = 64m x 12n = 768 blocks = 3.0
//    rounds of 256 CUs; proj = 64m x 4n = 256 blocks = 1.0 round.
//  * BN=192 divides 768 -> each block's columns live entirely inside one of
//    q/k/vt: epilogue 'which' is a per-block scalar.
// T2: chunk-XOR swizzle ch^=(row&7) via pre-swizzled global source (linear
// LDS dest, rule 21) + same XOR on the read side (0 conflicts measured).
// ---------------------------------------------------------------------------
template <int EPI>
__global__ __launch_bounds__(512, 2) void gemm128(
    const unsigned short* __restrict__ A, const unsigned short* __restrict__ Bt,
    unsigned short* __restrict__ qb, unsigned short* __restrict__ kb,
    unsigned short* __restrict__ vtb, float* __restrict__ outp,
    const float* __restrict__ bias) {
  constexpr int NKT = 12;    // 768 / 64
  constexpr int SSH = 20480; // shorts per stage: A 128x64 (8192) | B 192x64 (12288)
  __shared__ unsigned short smem[3 * SSH];  // 122,880 B

  const int t = threadIdx.x;                 // 0..511
  const int lane = t & 63, w = t >> 6;       // 8 waves
  const int quad = lane >> 4, l15 = lane & 15;
  const int wm = w >> 2, wn = w & 3;         // 2 m-bands x 4 n-bands

  const int bid = blockIdx.x;
  const int xcd = bid & 7, slot = bid >> 3;
  const int m0 = (xcd * 8 + (slot & 7)) * 128;  // m-minor within XCD
  const int n0 = (slot >> 3) * 192;

  // frag row offsets (shorts), loop-invariant. row&7 == l15&7 for all frags
  // (wave bases and 16-strides are multiples of 8).
  const int rs = l15 & 7;
  int arow[4], brow[3], co[2];
#pragma unroll
  for (int i = 0; i < 4; i++) arow[i] = (wm * 64 + i * 16 + l15) * 64;
#pragma unroll
  for (int j = 0; j < 3; j++) brow[j] = 8192 + (wn * 48 + j * 16 + l15) * 64;
#pragma unroll
  for (int kk = 0; kk < 2; kk++) co[kk] = ((kk * 4 + quad) ^ rs) << 3;

  // staging: thread t owns LDS slot t*16B within each 64-row group (linear,
  // DMA-compatible); slot = (row = srow, phys chunk = t&7); source supplies
  // logical chunk (t&7)^(srow&7).
  const int srow = t >> 3;                       // 0..63
  const int gch = ((t & 7) ^ (srow & 7)) << 3;   // source col offset (shorts)
  const unsigned short* Ags = A + (m0 + srow) * 768 + gch;
  const unsigned short* Bgs = Bt + (n0 + srow) * 768 + gch;

  f32x4 acc[4][3];
  const f32x4 fzero = {0.f, 0.f, 0.f, 0.f};
#pragma unroll
  for (int i = 0; i < 4; i++)
#pragma unroll
    for (int j = 0; j < 3; j++) acc[i][j] = fzero;

  // 5 loads per K-tile per thread (A: 2 x 64-row groups, B: 3).
  auto stage = [&](int kt) {
    unsigned short* s = smem + (kt % 3) * SSH + t * 8;
    const int ko = kt * 64;
    async16(Ags + ko, s);                    // A rows 0..63
    async16(Ags + 49152 + ko, s + 4096);     // A rows 64..127 (49152 = 64*768)
    async16(Bgs + ko, s + 8192);             // B rows 0..63
    async16(Bgs + 49152 + ko, s + 12288);    // B rows 64..127
    async16(Bgs + 98304 + ko, s + 16384);    // B rows 128..191
  };

  stage(0);
  stage(1);

#pragma unroll
  for (int kt = 0; kt < NKT; ++kt) {
    if (kt < NKT - 1) wait_vmcnt<5>();  // stage(kt) landed, stage(kt+1) flying
    else              wait_vmcnt<0>();
    __builtin_amdgcn_s_barrier();       // buf (kt+2)%3 free: all waves past kt-1

    if (kt + 2 < NKT) stage(kt + 2);    // DMA issue first: oldest VM ops

    const unsigned short* S = smem + (kt % 3) * SSH;
    bf16x8 af[2][4], bfr[2][3];
#pragma unroll
    for (int kk = 0; kk < 2; kk++) {
#pragma unroll
      for (int i = 0; i < 4; i++) af[kk][i] = ld_frag(S + arow[i] + co[kk]);
#pragma unroll
      for (int j = 0; j < 3; j++) bfr[kk][j] = ld_frag(S + brow[j] + co[kk]);
    }

    __builtin_amdgcn_s_setprio(1);
#pragma unroll
    for (int kk = 0; kk < 2; kk++)
#pragma unroll
      for (int i = 0; i < 4; i++)
#pragma unroll
        for (int j = 0; j < 3; j++)
          acc[i][j] = __builtin_amdgcn_mfma_f32_16x16x32_bf16(af[kk][i], bfr[kk][j], acc[i][j], 0, 0, 0);
    __builtin_amdgcn_s_setprio(0);
  }

  // Epilogue. C/D layout: row = quad*4+reg, col = lane&15 (verified m89/m91)
  // BN=192 | 768 -> whole block lies in one of q/k/vt.
  const int which = (n0 >= 1536) ? 2 : (n0 >= 768 ? 1 : 0);
  const int cwb = n0 - which * 768 + wn * 48;  // col within the 768-block
#pragma unroll
  for (int i = 0; i < 4; i++) {
    const int gmb = m0 + wm * 64 + i * 16 + quad * 4;
#pragma unroll
    for (int j = 0; j < 3; j++) {
      const int cw = cwb + j * 16 + l15;       // 0..767
#pragma unroll
      for (int r = 0; r < 4; r++) {
        const int gm = gmb + r;
        float v = acc[i][j][r];
        if (EPI == 0) {
          const int b = gm >> 10, tok = gm & 1023;
          const int h = cw >> 6, d = cw & 63;
          const int bh = b * 12 + h;
          const unsigned short bv = f2bf(v);
          if (which == 0)      qb[(bh << 16) + (tok << 6) + d] = bv;
          else if (which == 1) kb[(bh << 16) + (tok << 6) + d] = bv;
          else                 vtb[(bh << 16) + (d << 10) + tok] = bv;
        } else {
          outp[gm * 768 + n0 + wn * 48 + j * 16 + l15] = v + bias[n0 + wn * 48 + j * 16 + l15];
        }
      }
    }
  }
}

// ---------------------------------------------------------------------------
// Kernel 3: flash attention, S^T formulation (unchanged).
// ---------------------------------------------------------------------------
#define SWZC(row, c) (((row) << 6) + ((((c) + (row)) & 7) << 3))
#define C2 0.1803368801111244f  // SCALE * log2(e) = 0.125 * 1.442695...

__global__ __launch_bounds__(256, 3) void attn_kernel(
    const unsigned short* __restrict__ qb, const unsigned short* __restrict__ kb,
    const unsigned short* __restrict__ vtb, unsigned short* __restrict__ aout) {
  __shared__ unsigned short smem[3 * 8192];  // 48 KB: 3 stages of (Ks|Vts)

  const int t = threadIdx.x;
  const int lane = t & 63, w = t >> 6;
  const int quad = lane >> 4, l15 = lane & 15;
  const int bh = blockIdx.x;                   // bh fastest: q-tiles of one head
  const int b = bh / 12, h = bh - b * 12;      // land on the SAME XCD (96%8==0)
  const int q0 = blockIdx.y * 128;
  const int base = bh << 16;                   // bh * 1024 * 64

  // Q B-fragments, loop-invariant (issued before fills: oldest vm ops)
  bf16x8 qf[2][2];
#pragma unroll
  for (int qt = 0; qt < 2; qt++)
#pragma unroll
    for (int s = 0; s < 2; s++)
      qf[qt][s] = ld_frag(qb + base + ((q0 + w * 32 + qt * 16 + l15) << 6) +
                          s * 32 + quad * 8);

  f32x4 oacc[4][2];
  const f32x4 fzero = {0.f, 0.f, 0.f, 0.f};
#pragma unroll
  for (int dt = 0; dt < 4; dt++) { oacc[dt][0] = fzero; oacc[dt][1] = fzero; }
  float lsum0 = 0.f, lsum1 = 0.f;

  // staging slots: thread t fills LDS slot (row=t>>3, chunk=t&7); source chunk
  // de-swizzled so data lands at SWZC positions.
  const int srow = t >> 3, schk = t & 7;
  const int c0 = ((schk - srow) & 7) * 8;
  const int c1 = ((schk - (srow + 32)) & 7) * 8;

  auto fillkv = [&](int tile, int buf) {
    const int kv0 = tile * 64;
    unsigned short* Ks = smem + buf * 8192;
    unsigned short* Vts = Ks + 4096;
    async16(kb + base + ((kv0 + srow) << 6) + c0, Ks + t * 8);
    async16(kb + base + ((kv0 + srow + 32) << 6) + c1, Ks + 2048 + t * 8);
    async16(vtb + base + (srow << 10) + kv0 + c0, Vts + t * 8);
    async16(vtb + base + ((srow + 32) << 10) + kv0 + c1, Vts + 2048 + t * 8);
  };

  fillkv(0, 0);
  fillkv(1, 1);
  int cur = 0;
  for (int it = 0; it < 16; ++it) {
    if (it < 15) wait_vmcnt<4>(); else wait_vmcnt<0>();
    asm volatile("s_barrier" ::: "memory");
    if (it + 2 < 16) {
      int tgt = cur + 2; if (tgt >= 3) tgt -= 3;
      fillkv(it + 2, tgt);
    }
    const unsigned short* Ks = smem + cur * 8192;
    const unsigned short* Vts = Ks + 4096;

    // S^T = K Q^T : st[tc][qt], rows kv=tc*16+quad*4+r, col q=qt*16+l15
    f32x4 st[4][2];
#pragma unroll
    for (int tc = 0; tc < 4; tc++) { st[tc][0] = fzero; st[tc][1] = fzero; }
#pragma unroll
    for (int s = 0; s < 2; s++) {
#pragma unroll
      for (int tc = 0; tc < 4; tc++) {
        const bf16x8 kf = ld_frag(Ks + SWZC(tc * 16 + l15, s * 4 + quad));
        st[tc][0] = __builtin_amdgcn_mfma_f32_16x16x32_bf16(kf, qf[0][s], st[tc][0], 0, 0, 0);
        st[tc][1] = __builtin_amdgcn_mfma_f32_16x16x32_bf16(kf, qf[1][s], st[tc][1], 0, 0, 0);
      }
    }

    // P^T = exp2(S^T*C2); per-lane partial row sums; pack to x16 B-frags.
    s16x4 pf[4][2];
#pragma unroll
    for (int tc = 0; tc < 4; tc++) {
#pragma unroll
      for (int qt = 0; qt < 2; qt++) {
        const float p0 = fast_exp2(st[tc][qt][0] * C2);
        const float p1 = fast_exp2(st[tc][qt][1] * C2);
        const float p2 = fast_exp2(st[tc][qt][2] * C2);
        const float p3 = fast_exp2(st[tc][qt][3] * C2);
        const float ps = (p0 + p1) + (p2 + p3);
        if (qt == 0) lsum0 += ps; else lsum1 += ps;
        s16x4 pk;
        pk[0] = (short)f2bf(p0); pk[1] = (short)f2bf(p1);
        pk[2] = (short)f2bf(p2); pk[3] = (short)f2bf(p3);
        pf[tc][qt] = pk;
      }
    }

    // O^T += V^T P^T : x16 MFMA, A = V^T frag (8B LDS read), B = pf (regs)
#pragma unroll
    for (int tc = 0; tc < 4; tc++) {
#pragma unroll
      for (int dt = 0; dt < 4; dt++) {
        const int row = dt * 16 + l15;
        const int addr = (row << 6) + ((((tc * 2 + (quad >> 1)) + row) & 7) << 3) +
                         ((quad & 1) << 2);
        const s16x4 vf = *(const s16x4*)(Vts + addr);
        oacc[dt][0] = mfma16(vf, pf[tc][0], oacc[dt][0]);
        oacc[dt][1] = mfma16(vf, pf[tc][1], oacc[dt][1]);
      }
    }

    cur += 1; if (cur == 3) cur = 0;
  }

  // final row-sum reduction (only cross-lane ops in the kernel)
  lsum0 += __shfl_xor(lsum0, 16); lsum0 += __shfl_xor(lsum0, 32);
  lsum1 += __shfl_xor(lsum1, 16); lsum1 += __shfl_xor(lsum1, 32);
  const float inv0 = 1.f / lsum0, inv1 = 1.f / lsum1;

  // transpose O^T -> [q][d] via LDS (pad row to 72 elems: 2-way banks only)
  __syncthreads();  // all waves done with stage buffers before reuse
  unsigned short* Ot = smem;  // 128 x 72 = 9216 shorts
#pragma unroll
  for (int dt = 0; dt < 4; dt++) {
#pragma unroll
    for (int qt = 0; qt < 2; qt++) {
      const float inv = qt == 0 ? inv0 : inv1;
      const int qrow = (w * 32 + qt * 16 + l15) * 72 + dt * 16 + quad * 4;
#pragma unroll
      for (int r = 0; r < 4; r++)
        Ot[qrow + r] = f2bf(oacc[dt][qt][r] * inv);
    }
  }
  __syncthreads();
#pragma unroll
  for (int it = 0; it < 4; it++) {
    const int q = it * 32 + (t >> 3);
    const int d0 = (t & 7) * 8;
    const u16x8 v = *(const u16x8*)(Ot + q * 72 + d0);
    *(u16x8*)(aout + (b * 1024 + q0 + q) * 768 + h * 64 + d0) = v;
  }
}

// ---------------------------------------------------------------------------
// Launch
// ---------------------------------------------------------------------------
extern "C" void kernel_launch(void* const* d_in, const int* in_sizes, int n_in,
                              void* d_out, int out_size, void* d_ws, size_t ws_size,
                              hipStream_t stream) {
  (void)in_sizes; (void)n_in; (void)out_size; (void)ws_size;
  const float* x = (const float*)d_in[0];       // [8,1024,768]
  const float* w_qkv = (const float*)d_in[1];   // [768,2304]
  const float* w_proj = (const float*)d_in[2];  // [768,768]
  const float* b_proj = (const float*)d_in[3];  // [768]
  float* out = (float*)d_out;

  char* ws = (char*)d_ws;
  unsigned short* x_bf   = (unsigned short*)(ws);              // 12,582,912 B
  unsigned short* wqkvT  = (unsigned short*)(ws + 12582912);   //  3,538,944 B
  unsigned short* wprojT = (unsigned short*)(ws + 16121856);   //  1,179,648 B
  unsigned short* qb     = (unsigned short*)(ws + 17301504);   // 12,582,912 B
  unsigned short* kb     = (unsigned short*)(ws + 29884416);   // 12,582,912 B
  unsigned short* vtb    = (unsigned short*)(ws + 42467328);   // 12,582,912 B
  unsigned short* aout   = x_bf;  // reuse: x_bf dead after GEMM1

  prep_kernel<<<8448, 256, 0, stream>>>(x, w_qkv, w_proj, (u16x4*)x_bf, wqkvT, wprojT);
  gemm128<0><<<768, 512, 0, stream>>>(x_bf, wqkvT, qb, kb, vtb, nullptr, nullptr);
  attn_kernel<<<dim3(96, 8), 256, 0, stream>>>(qb, kb, vtb, aout);
  gemm128<1><<<256, 512, 0, stream>>>(aout, wprojT, nullptr, nullptr, nullptr, out, b_proj);
}

// Round 4
// 171.541 us; speedup vs baseline: 1.0893x; 1.0893x over previous
//
#include <hip/hip_runtime.h>
#include <stdint.h>

// ---------------------------------------------------------------------------
// Types
// ---------------------------------------------------------------------------
typedef __attribute__((ext_vector_type(8))) __bf16 bf16x8;
typedef __attribute__((ext_vector_type(8))) unsigned short u16x8;
typedef __attribute__((ext_vector_type(4))) unsigned short u16x4;
typedef __attribute__((ext_vector_type(4))) short s16x4;
typedef __attribute__((ext_vector_type(4))) float f32x4;

typedef unsigned int u32_as1 __attribute__((address_space(1)));
typedef unsigned int u32_as3 __attribute__((address_space(3)));

// fp32 -> bf16 round-to-nearest-even (inputs are finite normals; no NaN path)
__device__ __forceinline__ unsigned short f2bf(float f) {
  unsigned int u = __float_as_uint(f);
  u += 0x7fffu + ((u >> 16) & 1u);
  return (unsigned short)(u >> 16);
}

__device__ __forceinline__ bf16x8 ld_frag(const unsigned short* p) {
  return __builtin_bit_cast(bf16x8, *(const u16x8*)p);
}

// K=16 bf16 MFMA: A/B are 4 bf16 (as short4). C row=quad*4+r, col=lane&15;
// A[m=lane&15][k=quad*4+j]; B[k=quad*4+j][n=lane&15].
__device__ __forceinline__ f32x4 mfma16(s16x4 a, s16x4 b, f32x4 c) {
#if __has_builtin(__builtin_amdgcn_mfma_f32_16x16x16bf16_1k)
  return __builtin_amdgcn_mfma_f32_16x16x16bf16_1k(a, b, c, 0, 0, 0);
#elif __has_builtin(__builtin_amdgcn_mfma_f32_16x16x16_bf16_1k)
  return __builtin_amdgcn_mfma_f32_16x16x16_bf16_1k(a, b, c, 0, 0, 0);
#else
  asm volatile("v_mfma_f32_16x16x16_bf16 %0, %1, %2, %0"
               : "+v"(c) : "v"(a), "v"(b));
  return c;
#endif
}

__device__ __forceinline__ float fast_exp2(float x) {
#if __has_builtin(__builtin_amdgcn_exp2f)
  return __builtin_amdgcn_exp2f(x);
#else
  return exp2f(x);
#endif
}

// async global->LDS, 16B per lane. LDS dest must be wave-uniform base +
// lane*16B (linear); swizzled layouts come from pre-swizzling the per-lane
// GLOBAL source address (m97/m173 pattern).
__device__ __forceinline__ void async16(const void* g, void* l) {
  const u32_as1* gp = (const u32_as1*)(uintptr_t)g;
  u32_as3* lp = (u32_as3*)(uintptr_t)l;
  __builtin_amdgcn_global_load_lds(gp, lp, 16, 0, 0);
}

template <int N> __device__ __forceinline__ void wait_vmcnt() {
  if constexpr (N == 0)      asm volatile("s_waitcnt vmcnt(0)" ::: "memory");
  else if constexpr (N == 4) asm volatile("s_waitcnt vmcnt(4)" ::: "memory");
}

// ---------------------------------------------------------------------------
// Kernel 1: fused prep — x fp32->bf16, w_qkv / w_proj transpose+cast.
// ---------------------------------------------------------------------------
__global__ __launch_bounds__(256) void prep_kernel(
    const float* __restrict__ x, const float* __restrict__ w_qkv,
    const float* __restrict__ w_proj, u16x4* __restrict__ x_bf,
    unsigned short* __restrict__ wqkvT, unsigned short* __restrict__ wprojT) {
  const int bid = blockIdx.x;
  const int t = threadIdx.x;
  if (bid < 6144) {  // convert: 6144*256 float4 = 6,291,456 float4
    const int i = bid * 256 + t;
    float4 v = ((const float4*)x)[i];
    u16x4 o;
    o[0] = f2bf(v.x); o[1] = f2bf(v.y); o[2] = f2bf(v.z); o[3] = f2bf(v.w);
    x_bf[i] = o;
    return;
  }
  // transpose+cast, 32x32 tiles with flat 256 threads
  __shared__ float tile[32][33];
  const float* w; unsigned short* wt; int N, bx, by;
  if (bid < 6144 + 1728) { const int r = bid - 6144; w = w_qkv; wt = wqkvT; N = 2304; bx = r % 72; by = r / 72; }
  else                   { const int r = bid - 7872; w = w_proj; wt = wprojT; N = 768; bx = r % 24; by = r / 24; }
  const int n0 = bx * 32, k0 = by * 32;
  const int tx = t & 31, ty = t >> 5;
#pragma unroll
  for (int r = 0; r < 4; r++)
    tile[ty + r * 8][tx] = w[(k0 + ty + r * 8) * N + n0 + tx];
  __syncthreads();
#pragma unroll
  for (int r = 0; r < 4; r++)
    wt[(n0 + ty + r * 8) * 768 + k0 + tx] = f2bf(tile[tx][ty + r * 8]);
}

// ---------------------------------------------------------------------------
// Kernel 2/4: GEMM  C[M, 192-col tile] = A[M,768] * Bt[N,768]^T
// Template MW = #m-wave-bands: MW=2 -> 128x192 tile, 8 waves (512 thr);
// MW=1 -> 64x192 tile, 4 waves (256 thr). Wave C = 64x48 (acc[4][3]) both.
// Round-3 post-mortem fix: TLP via 2 blocks/CU.
//  * 2 LDS stages (MW=2: 81920 B = exactly 2 blocks/CU; MW=1: 65536 B ->
//    2 blocks/CU), distance-1 prefetch. vmcnt(0) at tile top drains
//    stage(kt) issued a FULL tile (~2300 cyc) earlier - far beyond the
//    ~900 cyc HBM latency, so the drain is cheap; cross-block TLP covers
//    the barrier convergence that 1-block/CU residency exposed (m114).
//  * __launch_bounds__(.., 4/2 waves-per-EU) forces regs <= 128 so both
//    blocks are co-resident; tile body is per-kk (7 live frags not 14).
//  * Grids: QKV 64m x 12n = 768 blocks = 1.5 rounds at 2/CU; proj
//    128m x 4n = 512 blocks = exactly 1.0 round at 2/CU.
// T2: chunk-XOR swizzle ch^=(row&7) via pre-swizzled global source (linear
// LDS dest, rule 21) + same XOR on the read side (0 conflicts measured).
// EPI=0: scatter -> q[b,h,n,d], k[b,h,n,d], vt[b,h,d,n] (bf16); EPI=1: +bias
// ---------------------------------------------------------------------------
template <int EPI, int MW>
__global__ __launch_bounds__(MW * 256, MW * 2) void gemm_bt(
    const unsigned short* __restrict__ A, const unsigned short* __restrict__ Bt,
    unsigned short* __restrict__ qb, unsigned short* __restrict__ kb,
    unsigned short* __restrict__ vtb, float* __restrict__ outp,
    const float* __restrict__ bias) {
  constexpr int NKT = 12;                 // 768 / 64
  constexpr int BM = MW * 64;
  constexpr int SSH = (BM + 192) * 64;    // shorts per stage (A | B)
  constexpr int MPX = (MW == 2) ? 8 : 16; // m-panels per XCD
  __shared__ unsigned short smem[2 * SSH];

  const int t = threadIdx.x;
  const int lane = t & 63, w = t >> 6;
  const int quad = lane >> 4, l15 = lane & 15;
  const int wm = w >> 2, wn = w & 3;      // MW m-bands x 4 n-bands

  const int bid = blockIdx.x;
  const int xcd = bid & 7, slot = bid >> 3;
  const int m0 = (xcd * MPX + (slot & (MPX - 1))) * BM;  // m-minor within XCD
  const int n0 = (slot / MPX) * 192;

  // frag offsets (shorts), loop-invariant. row&7 == l15&7 for all frags.
  const int rs = l15 & 7;
  int arow[4], brow[3], co[2];
#pragma unroll
  for (int i = 0; i < 4; i++) arow[i] = (wm * 64 + i * 16 + l15) * 64;
#pragma unroll
  for (int j = 0; j < 3; j++) brow[j] = BM * 64 + (wn * 48 + j * 16 + l15) * 64;
#pragma unroll
  for (int kk = 0; kk < 2; kk++) co[kk] = ((kk * 4 + quad) ^ rs) << 3;

  // staging: thread t owns LDS slot t*16B per 64-row group (linear, DMA-ok);
  // slot = (row srow, phys chunk t&7); source supplies logical chunk
  // (t&7)^(srow&7). (srow+32k)&7 == srow&7, so one gch serves all groups.
  const int srow = t >> 3;                       // MW=2: 0..63; MW=1: 0..31
  const int gch = ((t & 7) ^ (srow & 7)) << 3;
  const unsigned short* Ags = A + (m0 + srow) * 768 + gch;
  const unsigned short* Bgs = Bt + (n0 + srow) * 768 + gch;

  f32x4 acc[4][3];
  const f32x4 fzero = {0.f, 0.f, 0.f, 0.f};
#pragma unroll
  for (int i = 0; i < 4; i++)
#pragma unroll
    for (int j = 0; j < 3; j++) acc[i][j] = fzero;

  auto stage = [&](int kt) {
    unsigned short* s = smem + (kt & 1) * SSH + t * 8;
    const int ko = kt * 64;
    if constexpr (MW == 2) {  // 512 thr: 5 loads (A 2 groups, B 3)
      async16(Ags + ko, s);
      async16(Ags + 49152 + ko, s + 4096);     // 49152 = 64*768
      async16(Bgs + ko, s + 8192);
      async16(Bgs + 49152 + ko, s + 12288);
      async16(Bgs + 98304 + ko, s + 16384);
    } else {                  // 256 thr: 8 loads (A 64 rows, B 192 rows)
      async16(Ags + ko, s);
      async16(Ags + 24576 + ko, s + 2048);     // 24576 = 32*768
      async16(Bgs + ko, s + 4096);
      async16(Bgs + 24576 + ko, s + 6144);
      async16(Bgs + 49152 + ko, s + 8192);
      async16(Bgs + 73728 + ko, s + 10240);
      async16(Bgs + 98304 + ko, s + 12288);
      async16(Bgs + 122880 + ko, s + 14336);
    }
  };

  stage(0);

#pragma unroll
  for (int kt = 0; kt < NKT; ++kt) {
    wait_vmcnt<0>();               // stage(kt) landed (issued a full tile ago)
    __builtin_amdgcn_s_barrier();  // all waves past tile kt-1 reads
    if (kt + 1 < NKT) stage(kt + 1);  // overwrites buf of kt-1: safe

    const unsigned short* S = smem + (kt & 1) * SSH;
#pragma unroll
    for (int kk = 0; kk < 2; kk++) {
      bf16x8 af[4], bfr[3];
#pragma unroll
      for (int i = 0; i < 4; i++) af[i] = ld_frag(S + arow[i] + co[kk]);
#pragma unroll
      for (int j = 0; j < 3; j++) bfr[j] = ld_frag(S + brow[j] + co[kk]);
      __builtin_amdgcn_s_setprio(1);
#pragma unroll
      for (int i = 0; i < 4; i++)
#pragma unroll
        for (int j = 0; j < 3; j++)
          acc[i][j] = __builtin_amdgcn_mfma_f32_16x16x32_bf16(af[i], bfr[j], acc[i][j], 0, 0, 0);
      __builtin_amdgcn_s_setprio(0);
    }
  }

  // Epilogue. C/D layout: row = quad*4+reg, col = lane&15 (verified m89/m91)
  // BN=192 | 768 -> whole block lies in one of q/k/vt.
  const int which = (n0 >= 1536) ? 2 : (n0 >= 768 ? 1 : 0);
  const int cwb = n0 - which * 768 + wn * 48;  // col within the 768-block
#pragma unroll
  for (int i = 0; i < 4; i++) {
    const int gmb = m0 + wm * 64 + i * 16 + quad * 4;
#pragma unroll
    for (int j = 0; j < 3; j++) {
      const int cw = cwb + j * 16 + l15;       // 0..767
#pragma unroll
      for (int r = 0; r < 4; r++) {
        const int gm = gmb + r;
        float v = acc[i][j][r];
        if (EPI == 0) {
          const int b = gm >> 10, tok = gm & 1023;
          const int h = cw >> 6, d = cw & 63;
          const int bh = b * 12 + h;
          const unsigned short bv = f2bf(v);
          if (which == 0)      qb[(bh << 16) + (tok << 6) + d] = bv;
          else if (which == 1) kb[(bh << 16) + (tok << 6) + d] = bv;
          else                 vtb[(bh << 16) + (d << 10) + tok] = bv;
        } else {
          outp[gm * 768 + n0 + wn * 48 + j * 16 + l15] = v + bias[n0 + wn * 48 + j * 16 + l15];
        }
      }
    }
  }
}

// ---------------------------------------------------------------------------
// Kernel 3: flash attention, S^T formulation (unchanged).
// ---------------------------------------------------------------------------
#define SWZC(row, c) (((row) << 6) + ((((c) + (row)) & 7) << 3))
#define C2 0.1803368801111244f  // SCALE * log2(e) = 0.125 * 1.442695...

__global__ __launch_bounds__(256, 3) void attn_kernel(
    const unsigned short* __restrict__ qb, const unsigned short* __restrict__ kb,
    const unsigned short* __restrict__ vtb, unsigned short* __restrict__ aout) {
  __shared__ unsigned short smem[3 * 8192];  // 48 KB: 3 stages of (Ks|Vts)

  const int t = threadIdx.x;
  const int lane = t & 63, w = t >> 6;
  const int quad = lane >> 4, l15 = lane & 15;
  const int bh = blockIdx.x;                   // bh fastest: q-tiles of one head
  const int b = bh / 12, h = bh - b * 12;      // land on the SAME XCD (96%8==0)
  const int q0 = blockIdx.y * 128;
  const int base = bh << 16;                   // bh * 1024 * 64

  // Q B-fragments, loop-invariant (issued before fills: oldest vm ops)
  bf16x8 qf[2][2];
#pragma unroll
  for (int qt = 0; qt < 2; qt++)
#pragma unroll
    for (int s = 0; s < 2; s++)
      qf[qt][s] = ld_frag(qb + base + ((q0 + w * 32 + qt * 16 + l15) << 6) +
                          s * 32 + quad * 8);

  f32x4 oacc[4][2];
  const f32x4 fzero = {0.f, 0.f, 0.f, 0.f};
#pragma unroll
  for (int dt = 0; dt < 4; dt++) { oacc[dt][0] = fzero; oacc[dt][1] = fzero; }
  float lsum0 = 0.f, lsum1 = 0.f;

  // staging slots: thread t fills LDS slot (row=t>>3, chunk=t&7); source chunk
  // de-swizzled so data lands at SWZC positions.
  const int srow = t >> 3, schk = t & 7;
  const int c0 = ((schk - srow) & 7) * 8;
  const int c1 = ((schk - (srow + 32)) & 7) * 8;

  auto fillkv = [&](int tile, int buf) {
    const int kv0 = tile * 64;
    unsigned short* Ks = smem + buf * 8192;
    unsigned short* Vts = Ks + 4096;
    async16(kb + base + ((kv0 + srow) << 6) + c0, Ks + t * 8);
    async16(kb + base + ((kv0 + srow + 32) << 6) + c1, Ks + 2048 + t * 8);
    async16(vtb + base + (srow << 10) + kv0 + c0, Vts + t * 8);
    async16(vtb + base + ((srow + 32) << 10) + kv0 + c1, Vts + 2048 + t * 8);
  };

  fillkv(0, 0);
  fillkv(1, 1);
  int cur = 0;
  for (int it = 0; it < 16; ++it) {
    if (it < 15) wait_vmcnt<4>(); else wait_vmcnt<0>();
    asm volatile("s_barrier" ::: "memory");
    if (it + 2 < 16) {
      int tgt = cur + 2; if (tgt >= 3) tgt -= 3;
      fillkv(it + 2, tgt);
    }
    const unsigned short* Ks = smem + cur * 8192;
    const unsigned short* Vts = Ks + 4096;

    // S^T = K Q^T : st[tc][qt], rows kv=tc*16+quad*4+r, col q=qt*16+l15
    f32x4 st[4][2];
#pragma unroll
    for (int tc = 0; tc < 4; tc++) { st[tc][0] = fzero; st[tc][1] = fzero; }
#pragma unroll
    for (int s = 0; s < 2; s++) {
#pragma unroll
      for (int tc = 0; tc < 4; tc++) {
        const bf16x8 kf = ld_frag(Ks + SWZC(tc * 16 + l15, s * 4 + quad));
        st[tc][0] = __builtin_amdgcn_mfma_f32_16x16x32_bf16(kf, qf[0][s], st[tc][0], 0, 0, 0);
        st[tc][1] = __builtin_amdgcn_mfma_f32_16x16x32_bf16(kf, qf[1][s], st[tc][1], 0, 0, 0);
      }
    }

    // P^T = exp2(S^T*C2); per-lane partial row sums; pack to x16 B-frags.
    s16x4 pf[4][2];
#pragma unroll
    for (int tc = 0; tc < 4; tc++) {
#pragma unroll
      for (int qt = 0; qt < 2; qt++) {
        const float p0 = fast_exp2(st[tc][qt][0] * C2);
        const float p1 = fast_exp2(st[tc][qt][1] * C2);
        const float p2 = fast_exp2(st[tc][qt][2] * C2);
        const float p3 = fast_exp2(st[tc][qt][3] * C2);
        const float ps = (p0 + p1) + (p2 + p3);
        if (qt == 0) lsum0 += ps; else lsum1 += ps;
        s16x4 pk;
        pk[0] = (short)f2bf(p0); pk[1] = (short)f2bf(p1);
        pk[2] = (short)f2bf(p2); pk[3] = (short)f2bf(p3);
        pf[tc][qt] = pk;
      }
    }

    // O^T += V^T P^T : x16 MFMA, A = V^T frag (8B LDS read), B = pf (regs)
#pragma unroll
    for (int tc = 0; tc < 4; tc++) {
#pragma unroll
      for (int dt = 0; dt < 4; dt++) {
        const int row = dt * 16 + l15;
        const int addr = (row << 6) + ((((tc * 2 + (quad >> 1)) + row) & 7) << 3) +
                         ((quad & 1) << 2);
        const s16x4 vf = *(const s16x4*)(Vts + addr);
        oacc[dt][0] = mfma16(vf, pf[tc][0], oacc[dt][0]);
        oacc[dt][1] = mfma16(vf, pf[tc][1], oacc[dt][1]);
      }
    }

    cur += 1; if (cur == 3) cur = 0;
  }

  // final row-sum reduction (only cross-lane ops in the kernel)
  lsum0 += __shfl_xor(lsum0, 16); lsum0 += __shfl_xor(lsum0, 32);
  lsum1 += __shfl_xor(lsum1, 16); lsum1 += __shfl_xor(lsum1, 32);
  const float inv0 = 1.f / lsum0, inv1 = 1.f / lsum1;

  // transpose O^T -> [q][d] via LDS (pad row to 72 elems: 2-way banks only)
  __syncthreads();  // all waves done with stage buffers before reuse
  unsigned short* Ot = smem;  // 128 x 72 = 9216 shorts
#pragma unroll
  for (int dt = 0; dt < 4; dt++) {
#pragma unroll
    for (int qt = 0; qt < 2; qt++) {
      const float inv = qt == 0 ? inv0 : inv1;
      const int qrow = (w * 32 + qt * 16 + l15) * 72 + dt * 16 + quad * 4;
#pragma unroll
      for (int r = 0; r < 4; r++)
        Ot[qrow + r] = f2bf(oacc[dt][qt][r] * inv);
    }
  }
  __syncthreads();
#pragma unroll
  for (int it = 0; it < 4; it++) {
    const int q = it * 32 + (t >> 3);
    const int d0 = (t & 7) * 8;
    const u16x8 v = *(const u16x8*)(Ot + q * 72 + d0);
    *(u16x8*)(aout + (b * 1024 + q0 + q) * 768 + h * 64 + d0) = v;
  }
}

// ---------------------------------------------------------------------------
// Launch
// ---------------------------------------------------------------------------
extern "C" void kernel_launch(void* const* d_in, const int* in_sizes, int n_in,
                              void* d_out, int out_size, void* d_ws, size_t ws_size,
                              hipStream_t stream) {
  (void)in_sizes; (void)n_in; (void)out_size; (void)ws_size;
  const float* x = (const float*)d_in[0];       // [8,1024,768]
  const float* w_qkv = (const float*)d_in[1];   // [768,2304]
  const float* w_proj = (const float*)d_in[2];  // [768,768]
  const float* b_proj = (const float*)d_in[3];  // [768]
  float* out = (float*)d_out;

  char* ws = (char*)d_ws;
  unsigned short* x_bf   = (unsigned short*)(ws);              // 12,582,912 B
  unsigned short* wqkvT  = (unsigned short*)(ws + 12582912);   //  3,538,944 B
  unsigned short* wprojT = (unsigned short*)(ws + 16121856);   //  1,179,648 B
  unsigned short* qb     = (unsigned short*)(ws + 17301504);   // 12,582,912 B
  unsigned short* kb     = (unsigned short*)(ws + 29884416);   // 12,582,912 B
  unsigned short* vtb    = (unsigned short*)(ws + 42467328);   // 12,582,912 B
  unsigned short* aout   = x_bf;  // reuse: x_bf dead after GEMM1

  prep_kernel<<<8448, 256, 0, stream>>>(x, w_qkv, w_proj, (u16x4*)x_bf, wqkvT, wprojT);
  gemm_bt<0, 2><<<768, 512, 0, stream>>>(x_bf, wqkvT, qb, kb, vtb, nullptr, nullptr);
  attn_kernel<<<dim3(96, 8), 256, 0, stream>>>(qb, kb, vtb, aout);
  gemm_bt<1, 1><<<512, 256, 0, stream>>>(aout, wprojT, nullptr, nullptr, nullptr, out, b_proj);
}